// Round 2
// baseline (286.971 us; speedup 1.0000x reference)
//
#include <hip/hip_runtime.h>

#define NB 64  // n_bins (bins array has NB+1 edges)

typedef float vfloat4 __attribute__((ext_vector_type(4)));

__global__ __launch_bounds__(256) void ple_kernel(const float* __restrict__ x,
                                                  const float* __restrict__ bins,
                                                  float* __restrict__ out,
                                                  int batch) {
    __shared__ float s_lo[NB];
    __shared__ float s_hi[NB];

    const int tid = threadIdx.x;
    if (tid < NB) {
        s_lo[tid] = bins[tid];
        s_hi[tid] = bins[tid + 1];
    }
    __syncthreads();

    // One float4 of output per thread: 16 threads cover one x (64 bins).
    const long long t = (long long)blockIdx.x * blockDim.x + tid;  // float4 index
    const long long total4 = (long long)batch * (NB / 4);
    if (t >= total4) return;

    const int i  = (int)(t >> 4);          // batch index
    const int j4 = ((int)t & 15) << 2;     // first bin of this group of 4

    const float xv = x[i];

    const vfloat4 lo4 = *(const vfloat4*)&s_lo[j4];
    const vfloat4 hi4 = *(const vfloat4*)&s_hi[j4];

    // enc = 0 if (x <  lo && j > 0)
    //       1 if (x >= hi && j < NB-1)
    //       (x - lo)/(hi - lo) otherwise
    vfloat4 r;
#pragma unroll
    for (int k = 0; k < 4; ++k) {
        const float lo = lo4[k];
        const float hi = hi4[k];
        const float v  = (xv - lo) / (hi - lo);
        const int j = j4 + k;
        r[k] = (xv < lo && j > 0) ? 0.0f : ((xv >= hi && j < NB - 1) ? 1.0f : v);
    }

    __builtin_nontemporal_store(r, (vfloat4*)out + t);
}

extern "C" void kernel_launch(void* const* d_in, const int* in_sizes, int n_in,
                              void* d_out, int out_size, void* d_ws, size_t ws_size,
                              hipStream_t stream) {
    const float* x    = (const float*)d_in[0];
    const float* bins = (const float*)d_in[1];
    float* out        = (float*)d_out;

    const int batch = in_sizes[0];                 // x is (BATCH, 1)
    const long long total4 = (long long)batch * (NB / 4);
    const int block = 256;
    const long long grid = (total4 + block - 1) / block;

    ple_kernel<<<(dim3)(unsigned)grid, block, 0, stream>>>(x, bins, out, batch);
}

// Round 3
// 260.656 us; speedup vs baseline: 1.1010x; 1.1010x over previous
//
#include <hip/hip_runtime.h>
#include <float.h>

#define NB 64  // n_bins (bins array has NB+1 edges)

typedef float vfloat4 __attribute__((ext_vector_type(4)));

__global__ __launch_bounds__(256) void ple_kernel(const float* __restrict__ x,
                                                  const float* __restrict__ bins,
                                                  float* __restrict__ out,
                                                  long long total4) {
    // Per-bin precomputed params: v = fma(x, rinv, nlor); enc = clamp(v, cl, ch)
    __shared__ __align__(16) float s_rinv[NB];
    __shared__ __align__(16) float s_nlor[NB];
    __shared__ __align__(16) float s_cl[NB];
    __shared__ __align__(16) float s_ch[NB];

    const int tid = threadIdx.x;
    if (tid < NB) {
        const float lo   = bins[tid];
        const float hi   = bins[tid + 1];
        const float rinv = 1.0f / (hi - lo);   // 64 divides per block, off the hot path
        s_rinv[tid] = rinv;
        s_nlor[tid] = -lo * rinv;
        // j==0: no left clamp (negative v passes through); j==NB-1: no right clamp
        s_cl[tid] = (tid == 0)      ? -FLT_MAX : 0.0f;
        s_ch[tid] = (tid == NB - 1) ?  FLT_MAX : 1.0f;
    }
    __syncthreads();

    // Each thread owns bins [j4, j4+4) of every 16th float4-slot; loop-invariant.
    const int j4 = (tid & 15) << 2;
    const vfloat4 rinv4 = *(const vfloat4*)&s_rinv[j4];
    const vfloat4 nlor4 = *(const vfloat4*)&s_nlor[j4];
    const vfloat4 cl4   = *(const vfloat4*)&s_cl[j4];
    const vfloat4 ch4   = *(const vfloat4*)&s_ch[j4];

    const long long stride = (long long)gridDim.x * blockDim.x;  // multiple of 16
    for (long long t = (long long)blockIdx.x * blockDim.x + tid; t < total4; t += stride) {
        const float xv = x[t >> 4];  // 16 lanes share one x -> broadcast
        vfloat4 r;
#pragma unroll
        for (int k = 0; k < 4; ++k) {
            const float v = fmaf(xv, rinv4[k], nlor4[k]);
            r[k] = fminf(fmaxf(v, cl4[k]), ch4[k]);
        }
        __builtin_nontemporal_store(r, (vfloat4*)out + t);
    }
}

extern "C" void kernel_launch(void* const* d_in, const int* in_sizes, int n_in,
                              void* d_out, int out_size, void* d_ws, size_t ws_size,
                              hipStream_t stream) {
    const float* x    = (const float*)d_in[0];
    const float* bins = (const float*)d_in[1];
    float* out        = (float*)d_out;

    const int batch = in_sizes[0];                 // x is (BATCH, 1)
    const long long total4 = (long long)batch * (NB / 4);

    const int block = 256;
    int grid = 2048;                               // 8 blocks/CU across 256 CUs
    const long long need = (total4 + block - 1) / block;
    if (need < grid) grid = (int)need;

    ple_kernel<<<grid, block, 0, stream>>>(x, bins, out, total4);
}

// Round 4
// 248.683 us; speedup vs baseline: 1.1540x; 1.0481x over previous
//
#include <hip/hip_runtime.h>
#include <float.h>

#define NB 64  // n_bins (bins array has NB+1 edges)

typedef float vfloat4 __attribute__((ext_vector_type(4)));

// Each block covers 1024 consecutive float4-slots (256 threads x 4 slots at
// +256 stride). 4 independent x loads per thread issue together -> 4x MLP.
__global__ __launch_bounds__(256) void ple_kernel(const float* __restrict__ x,
                                                  const float* __restrict__ bins,
                                                  float* __restrict__ out,
                                                  long long total4) {
    __shared__ __align__(16) float s_rinv[NB];
    __shared__ __align__(16) float s_nlor[NB];
    __shared__ __align__(16) float s_cl[NB];
    __shared__ __align__(16) float s_ch[NB];

    const int tid = threadIdx.x;
    if (tid < NB) {
        const float lo   = bins[tid];
        const float hi   = bins[tid + 1];
        const float rinv = 1.0f / (hi - lo);   // off the hot path: once per block
        s_rinv[tid] = rinv;
        s_nlor[tid] = -lo * rinv;
        s_cl[tid] = (tid == 0)      ? -FLT_MAX : 0.0f;   // bin 0: no left clamp
        s_ch[tid] = (tid == NB - 1) ?  FLT_MAX : 1.0f;   // bin 63: no right clamp
    }
    __syncthreads();

    const int j4 = (tid & 15) << 2;            // this thread's 4 bins (loop-invariant)
    const vfloat4 rinv4 = *(const vfloat4*)&s_rinv[j4];
    const vfloat4 nlor4 = *(const vfloat4*)&s_nlor[j4];
    const vfloat4 cl4   = *(const vfloat4*)&s_cl[j4];
    const vfloat4 ch4   = *(const vfloat4*)&s_ch[j4];

    const long long base = (long long)blockIdx.x * 1024 + tid;

    long long t[4];
    float xv[4];
#pragma unroll
    for (int k = 0; k < 4; ++k) {              // 4 independent loads, issued together
        t[k] = base + (long long)(k << 8);
        xv[k] = (t[k] < total4) ? x[t[k] >> 4] : 0.0f;
    }

#pragma unroll
    for (int k = 0; k < 4; ++k) {
        vfloat4 r;
#pragma unroll
        for (int c = 0; c < 4; ++c) {
            const float v = fmaf(xv[k], rinv4[c], nlor4[c]);
            r[c] = fminf(fmaxf(v, cl4[c]), ch4[c]);
        }
        if (t[k] < total4)
            __builtin_nontemporal_store(r, (vfloat4*)out + t[k]);
    }
}

extern "C" void kernel_launch(void* const* d_in, const int* in_sizes, int n_in,
                              void* d_out, int out_size, void* d_ws, size_t ws_size,
                              hipStream_t stream) {
    const float* x    = (const float*)d_in[0];
    const float* bins = (const float*)d_in[1];
    float* out        = (float*)d_out;

    const int batch = in_sizes[0];                   // x is (BATCH, 1)
    const long long total4 = (long long)batch * (NB / 4);
    const long long grid = (total4 + 1023) / 1024;   // 15625 for BATCH=1e6 (exact)

    ple_kernel<<<(dim3)(unsigned)grid, 256, 0, stream>>>(x, bins, out, total4);
}

// Round 5
// 246.012 us; speedup vs baseline: 1.1665x; 1.0109x over previous
//
#include <hip/hip_runtime.h>
#include <float.h>

#define NB 64  // n_bins (bins array has NB+1 edges)

typedef float vfloat4 __attribute__((ext_vector_type(4)));

// Each block covers 1024 consecutive float4-slots (256 threads x 4 slots at
// +256 stride). 4 independent x loads per thread issue together -> 4x MLP.
// Stores are PLAIN (write-back via L2): the harness fill kernel sustains
// 6.3 TB/s with plain stores; R4's nt-flagged stores measured ~3.1 TB/s.
__global__ __launch_bounds__(256) void ple_kernel(const float* __restrict__ x,
                                                  const float* __restrict__ bins,
                                                  float* __restrict__ out,
                                                  long long total4) {
    __shared__ __align__(16) float s_rinv[NB];
    __shared__ __align__(16) float s_nlor[NB];
    __shared__ __align__(16) float s_cl[NB];
    __shared__ __align__(16) float s_ch[NB];

    const int tid = threadIdx.x;
    if (tid < NB) {
        const float lo   = bins[tid];
        const float hi   = bins[tid + 1];
        const float rinv = 1.0f / (hi - lo);   // off the hot path: once per block
        s_rinv[tid] = rinv;
        s_nlor[tid] = -lo * rinv;
        s_cl[tid] = (tid == 0)      ? -FLT_MAX : 0.0f;   // bin 0: no left clamp
        s_ch[tid] = (tid == NB - 1) ?  FLT_MAX : 1.0f;   // bin 63: no right clamp
    }
    __syncthreads();

    const int j4 = (tid & 15) << 2;            // this thread's 4 bins (loop-invariant)
    const vfloat4 rinv4 = *(const vfloat4*)&s_rinv[j4];
    const vfloat4 nlor4 = *(const vfloat4*)&s_nlor[j4];
    const vfloat4 cl4   = *(const vfloat4*)&s_cl[j4];
    const vfloat4 ch4   = *(const vfloat4*)&s_ch[j4];

    const long long base = (long long)blockIdx.x * 1024 + tid;

    long long t[4];
    float xv[4];
#pragma unroll
    for (int k = 0; k < 4; ++k) {              // 4 independent loads, issued together
        t[k] = base + (long long)(k << 8);
        xv[k] = (t[k] < total4) ? x[t[k] >> 4] : 0.0f;
    }

#pragma unroll
    for (int k = 0; k < 4; ++k) {
        vfloat4 r;
#pragma unroll
        for (int c = 0; c < 4; ++c) {
            const float v = fmaf(xv[k], rinv4[c], nlor4[c]);
            r[c] = fminf(fmaxf(v, cl4[c]), ch4[c]);
        }
        if (t[k] < total4)
            *((vfloat4*)out + t[k]) = r;       // plain store (write-back L2 path)
    }
}

extern "C" void kernel_launch(void* const* d_in, const int* in_sizes, int n_in,
                              void* d_out, int out_size, void* d_ws, size_t ws_size,
                              hipStream_t stream) {
    const float* x    = (const float*)d_in[0];
    const float* bins = (const float*)d_in[1];
    float* out        = (float*)d_out;

    const int batch = in_sizes[0];                   // x is (BATCH, 1)
    const long long total4 = (long long)batch * (NB / 4);
    const long long grid = (total4 + 1023) / 1024;   // 15625 for BATCH=1e6 (exact)

    ple_kernel<<<(dim3)(unsigned)grid, 256, 0, stream>>>(x, bins, out, total4);
}